// Round 6
// baseline (144.709 us; speedup 1.0000x reference)
//
#include <hip/hip_runtime.h>

// Backward warp, bilinear sampling. B=16, H=W=1024 (pow2, hardcoded), C=3, fp32.
// 2x2 px/thread inside a 64w x 16h block tile: quadruples gather MLP per wave
// (latency-bound per R5 counters: BW 25%, VALU 17%, occ 84% -> nothing saturated),
// halves flow-load instrs, vectorizes stores. Block gather footprint ~28KB (L1-fit).
// Fused row-pair gathers (24B cover both x-corners), nontemporal flow/out,
// vertical tile order + XCD-chunked swizzle for L2 reuse.

struct __attribute__((packed, aligned(4))) R6 { float v[6]; };
typedef float f4 __attribute__((ext_vector_type(4), aligned(8)));
typedef float f2 __attribute__((ext_vector_type(2), aligned(8)));

__global__ __launch_bounds__(256) void backwarp_kernel(
    const float* __restrict__ image,
    const float* __restrict__ flow,
    float* __restrict__ out) {
  constexpr int H = 1024, W = 1024;
  constexpr int NB = 16384;        // 16 batches * 16 tiles_x * 64 tiles_y
  constexpr int CHUNK = NB / 8;

  // XCD-chunked swizzle (16384 % 8 == 0 -> bijective)
  int bid = blockIdx.x;
  int sb = (bid & 7) * CHUNK + (bid >> 3);

  // vertical-adjacency order: tile_y fastest
  int b      = sb >> 10;           // 1024 tiles per batch
  int r      = sb & 1023;
  int tile_x = r >> 6;             // [0,16)
  int tile_y = r & 63;             // [0,64)

  int qx = threadIdx.x & 31;       // quad col [0,32)
  int qy = threadIdx.x >> 5;       // quad row [0,8)
  int w0 = (tile_x << 6) + (qx << 1);
  int h0 = (tile_y << 4) + (qy << 1);
  int plane = b << 20;

#pragma unroll
  for (int dy = 0; dy < 2; ++dy) {
    int h = h0 + dy;
    int idx0 = plane + (h << 10) + w0;    // even -> flow f4 16B-aligned
    f4 fl = __builtin_nontemporal_load(
        reinterpret_cast<const f4*>(flow + (size_t)idx0 * 2));
    float res[6];
#pragma unroll
    for (int dx = 0; dx < 2; ++dx) {
      float x = (float)(w0 + dx) + (dx ? fl.z : fl.x);
      float y = (float)h + (dx ? fl.w : fl.y);
      // faithful round-trip from the reference (x/1024 == x*(1/1024) exactly)
      x = 0.5f * (2.0f * (x * (1.0f / W) - 0.5f) + 1.0f) * W;
      y = 0.5f * (2.0f * (y * (1.0f / H) - 0.5f) + 1.0f) * H;

      int x0 = (int)x;             // trunc toward zero, like astype(int32)
      int y0 = (int)y;
      int x1 = x0 + 1;
      int y1 = y0 + 1;
      x0 = min(max(x0, 0), W - 1);
      x1 = min(max(x1, 0), W - 1);
      y0 = min(max(y0, 0), H - 1);
      y1 = min(max(y1, 0), H - 1);

      float wa = ((float)x1 - x) * ((float)y1 - y);
      float wb = ((float)x1 - x) * (y - (float)y0);
      float wc = (x - (float)x0) * ((float)y1 - y);
      float wd = (x - (float)x0) * (y - (float)y0);

      // Fused gather: 6 contiguous floats at bx cover pixels {bx, bx+1};
      // select halves for (x0, x1) including all border-clamp cases.
      int bx = min(x0, W - 2);
      bool hiA = (x0 != bx);       // pa lives in v[3..5]
      bool hiC = (x1 != bx);       // pc lives in v[3..5]

      const R6 r0 = *reinterpret_cast<const R6*>(image + (size_t)(plane + (y0 << 10) + bx) * 3);
      const R6 r1 = *reinterpret_cast<const R6*>(image + (size_t)(plane + (y1 << 10) + bx) * 3);

#pragma unroll
      for (int c = 0; c < 3; ++c) {
        float pa  = hiA ? r0.v[3 + c] : r0.v[c];
        float pc_ = hiC ? r0.v[3 + c] : r0.v[c];
        float pb  = hiA ? r1.v[3 + c] : r1.v[c];
        float pd  = hiC ? r1.v[3 + c] : r1.v[c];
        res[dx * 3 + c] = wa * pa + wb * pb + wc * pc_ + wd * pd;
      }
    }
    // 2 px = 24B contiguous; idx0 even -> byte offset 24B-aligned (>=8B align)
    float* o = out + (size_t)idx0 * 3;
    f4 s0 = {res[0], res[1], res[2], res[3]};
    f2 s1 = {res[4], res[5]};
    __builtin_nontemporal_store(s0, reinterpret_cast<f4*>(o));
    __builtin_nontemporal_store(s1, reinterpret_cast<f2*>(o + 4));
  }
}

extern "C" void kernel_launch(void* const* d_in, const int* in_sizes, int n_in,
                              void* d_out, int out_size, void* d_ws, size_t ws_size,
                              hipStream_t stream) {
  const float* image = (const float*)d_in[0];
  const float* flow  = (const float*)d_in[1];
  float* out = (float*)d_out;

  backwarp_kernel<<<16384, 256, 0, stream>>>(image, flow, out);
}